// Round 2
// baseline (22156.090 us; speedup 1.0000x reference)
//
#include <hip/hip_runtime.h>

#define B_   256
#define T_   512
#define IN_  34
#define H_   80
#define L_   10
#define NC_  5
#define G4   320        // 4*H
#define TPB  640        // 2 threads per gate row (A: W_ih half, B: W_hh half)
#define CH   256        // chunk timesteps
#define NCH  2          // T_/CH

__device__ __forceinline__ float sigm(float x)     { return 1.f / (1.f + __expf(-x)); }
__device__ __forceinline__ float tanhfast(float x) { return 1.f - 2.f / (__expf(2.f * x) + 1.f); }

__global__ __launch_bounds__(TPB, 2) void lstm_stack_kernel(
    const float* __restrict__ x,     // [B,T,34]
    const float* __restrict__ Wih0,  // [320,34]
    const float* __restrict__ WihR,  // [9,320,80]
    const float* __restrict__ Whh,   // [10,320,80]
    const float* __restrict__ bih,   // [10,320]
    const float* __restrict__ bhh,   // [10,320]
    const float* __restrict__ fcw,   // [5,80]
    const float* __restrict__ fcb,   // [5]
    float* __restrict__ out)         // [B,5]
{
    const int b   = blockIdx.x;
    const int tid = threadIdx.x;          // 0..639
    const bool isA = tid < G4;            // waves 0-4: input-half, waves 5-9: hidden-half
    const int g   = isA ? tid : tid - G4; // gate row 0..319

    __shared__ __align__(16) float hist[CH][H_];   // 80 KB: inter-layer h history (in-place)
    __shared__ __align__(16) float xbuf[CH][36];   // 36 KB: layer-0 input chunk (padded 34->36)
    __shared__ __align__(16) float hs[H_];         // current h(t-1)
    __shared__ float gshA[G4];                     // x-half partial (+bias)
    __shared__ float gshB[G4];                     // h-half partial
    __shared__ float hstate[L_][H_];               // per-layer h carry across chunks
    __shared__ float cstate[L_][H_];               // per-layer c carry across chunks

    // zero carry state
    for (int i = tid; i < L_ * H_; i += TPB) { hstate[i / H_][i % H_] = 0.f; cstate[i / H_][i % H_] = 0.f; }
    __syncthreads();

    for (int c = 0; c < NCH; ++c) {
        // ---- stage x chunk into LDS (coalesced) ----
        const float* xsrc = x + ((size_t)b * T_ + (size_t)c * CH) * IN_;
        for (int i = tid; i < CH * IN_; i += TPB) xbuf[i / IN_][i % IN_] = xsrc[i];
        for (int i = tid; i < CH; i += TPB) { xbuf[i][34] = 0.f; xbuf[i][35] = 0.f; }
        __syncthreads();

        for (int l = 0; l < L_; ++l) {
            const bool l0 = (l == 0);

            // ---- load this thread's weight half into registers ----
            float w[H_];
            float bias = 0.f;
            if (isA) {
                if (l0) {
                    const float* p = Wih0 + (size_t)g * IN_;
#pragma unroll
                    for (int k = 0; k < IN_; ++k) w[k] = p[k];
                    w[34] = 0.f; w[35] = 0.f;
                } else {
                    const float4* p = (const float4*)(WihR + ((size_t)(l - 1) * G4 + g) * H_);
#pragma unroll
                    for (int k = 0; k < H_ / 4; ++k) {
                        float4 v = p[k];
                        w[4 * k] = v.x; w[4 * k + 1] = v.y; w[4 * k + 2] = v.z; w[4 * k + 3] = v.w;
                    }
                }
                bias = bih[l * G4 + g] + bhh[l * G4 + g];
            } else {
                const float4* p = (const float4*)(Whh + ((size_t)l * G4 + g) * H_);
#pragma unroll
                for (int k = 0; k < H_ / 4; ++k) {
                    float4 v = p[k];
                    w[4 * k] = v.x; w[4 * k + 1] = v.y; w[4 * k + 2] = v.z; w[4 * k + 3] = v.w;
                }
            }

            // ---- restore carry state ----
            if (tid < H_) hs[tid] = hstate[l][tid];
            float creg = (tid < H_) ? cstate[l][tid] : 0.f;
            __syncthreads();

            // ---- time scan over this chunk ----
            for (int t = 0; t < CH; ++t) {
                float a0 = 0.f, a1 = 0.f, a2 = 0.f, a3 = 0.f;
                if (isA) {
                    if (l0) {
                        const float4* s4 = (const float4*)xbuf[t];
#pragma unroll
                        for (int k = 0; k < 9; ++k) {
                            float4 v = s4[k];
                            a0 += w[4 * k] * v.x; a1 += w[4 * k + 1] * v.y;
                            a2 += w[4 * k + 2] * v.z; a3 += w[4 * k + 3] * v.w;
                        }
                    } else {
                        const float4* s4 = (const float4*)hist[t];
#pragma unroll
                        for (int k = 0; k < H_ / 4; ++k) {
                            float4 v = s4[k];
                            a0 += w[4 * k] * v.x; a1 += w[4 * k + 1] * v.y;
                            a2 += w[4 * k + 2] * v.z; a3 += w[4 * k + 3] * v.w;
                        }
                    }
                    gshA[g] = bias + (a0 + a1) + (a2 + a3);
                } else {
                    const float4* s4 = (const float4*)hs;
#pragma unroll
                    for (int k = 0; k < H_ / 4; ++k) {
                        float4 v = s4[k];
                        a0 += w[4 * k] * v.x; a1 += w[4 * k + 1] * v.y;
                        a2 += w[4 * k + 2] * v.z; a3 += w[4 * k + 3] * v.w;
                    }
                    gshB[g] = (a0 + a1) + (a2 + a3);
                }
                __syncthreads();   // gsh ready; all hist[t]/hs reads complete

                if (tid < H_) {
                    float gi = sigm(gshA[tid] + gshB[tid]);
                    float gf = sigm(gshA[tid + H_] + gshB[tid + H_]);
                    float gg = tanhfast(gshA[tid + 2 * H_] + gshB[tid + 2 * H_]);
                    float go = sigm(gshA[tid + 3 * H_] + gshB[tid + 3 * H_]);
                    creg = gf * creg + gi * gg;
                    float h = go * tanhfast(creg);
                    hs[tid] = h;
                    hist[t][tid] = h;    // in-place: this t already consumed this step
                }
                __syncthreads();   // hs / hist[t] ready for next step / next layer
            }

            // ---- save carry state ----
            if (tid < H_) { hstate[l][tid] = hs[tid]; cstate[l][tid] = creg; }
            __syncthreads();
        }
    }

    // ---- fc on last timestep's hidden state (in hs) ----
    if (tid < NC_) {
        float acc = fcb[tid];
#pragma unroll
        for (int j = 0; j < H_; ++j) acc += fcw[tid * H_ + j] * hs[j];
        out[b * NC_ + tid] = acc;
    }
}

extern "C" void kernel_launch(void* const* d_in, const int* in_sizes, int n_in,
                              void* d_out, int out_size, void* d_ws, size_t ws_size,
                              hipStream_t stream) {
    const float* x    = (const float*)d_in[0];
    const float* Wih0 = (const float*)d_in[1];
    const float* WihR = (const float*)d_in[2];
    const float* Whh  = (const float*)d_in[3];
    const float* bih  = (const float*)d_in[4];
    const float* bhh  = (const float*)d_in[5];
    const float* fcw  = (const float*)d_in[6];
    const float* fcb  = (const float*)d_in[7];

    lstm_stack_kernel<<<dim3(B_), dim3(TPB), 0, stream>>>(
        x, Wih0, WihR, Whh, bih, bhh, fcw, fcb, (float*)d_out);
}

// Round 3
// 5441.906 us; speedup vs baseline: 4.0714x; 4.0714x over previous
//
#include <hip/hip_runtime.h>

#define B_   256
#define T_   512
#define IN_  34
#define H_   80
#define L_   10
#define NC_  5
#define G4   320        // 4*H
#define TPB  640        // 2 threads per gate row: A half (W_ih) + B half (W_hh)
#define CH   256        // chunk timesteps held in LDS
#define NCH  2          // T_/CH

__device__ __forceinline__ float sigm(float x)     { return 1.f / (1.f + __expf(-x)); }
__device__ __forceinline__ float tanhfast(float x) { return 1.f - 2.f / (__expf(2.f * x) + 1.f); }

// Pack weights into branch-free layout: wbuf[l][half][g][k], half 0 = W_ih (layer0
// zero-padded 34->80), half 1 = W_hh. bbuf[l][g] = b_ih + b_hh.
__global__ void prep_kernel(const float* __restrict__ Wih0, const float* __restrict__ WihR,
                            const float* __restrict__ Whh,  const float* __restrict__ bih,
                            const float* __restrict__ bhh,
                            float* __restrict__ wbuf, float* __restrict__ bbuf) {
    int i = blockIdx.x * 256 + threadIdx.x;
    const int NW = L_ * 2 * G4 * H_;   // 512000
    if (i < NW) {
        int k = i % H_;
        int g = (i / H_) % G4;
        int half = (i / (H_ * G4)) % 2;
        int l = i / (H_ * G4 * 2);
        float v;
        if (half) v = Whh[((size_t)l * G4 + g) * H_ + k];
        else if (l == 0) v = (k < IN_) ? Wih0[g * IN_ + k] : 0.f;
        else v = WihR[((size_t)(l - 1) * G4 + g) * H_ + k];
        wbuf[i] = v;
    }
    if (i < L_ * G4) bbuf[i] = bih[i] + bhh[i];
}

__global__ __launch_bounds__(TPB) __attribute__((amdgpu_waves_per_eu(1)))
void lstm_stack_kernel(
    const float* __restrict__ x,     // [B,T,34]
    const float* __restrict__ wbuf,  // [10][2][320][80]
    const float* __restrict__ bbuf,  // [10][320]
    const float* __restrict__ fcw,   // [5,80]
    const float* __restrict__ fcb,   // [5]
    float* __restrict__ out)         // [B,5]
{
    const int b   = blockIdx.x;
    const int tid = threadIdx.x;          // 0..639
    const bool isA = tid < G4;            // waves 0-4: W_ih half, waves 5-9: W_hh half
    const int g   = isA ? tid : tid - G4; // gate row 0..319

    __shared__ __align__(16) float hist[CH][H_];   // 80 KB inter-layer h history (in-place)
    __shared__ __align__(16) float hs[H_];         // h(t-1) of current layer
    __shared__ float gshA[G4];
    __shared__ float gshB[G4];
    __shared__ float hstate[L_][H_];
    __shared__ float cstate[L_][H_];

    for (int i = tid; i < L_ * H_; i += TPB) {
        (&hstate[0][0])[i] = 0.f;
        (&cstate[0][0])[i] = 0.f;
    }

    for (int c = 0; c < NCH; ++c) {
        __syncthreads();
        // stage x chunk into hist, zero-padded 34 -> 80 (layer 0 == generic layer)
        const float* xsrc = x + ((size_t)b * T_ + (size_t)c * CH) * IN_;
        for (int i = tid; i < CH * IN_; i += TPB) hist[i / IN_][i % IN_] = xsrc[i];
        for (int i = tid; i < CH * (H_ - IN_); i += TPB)
            hist[i / (H_ - IN_)][IN_ + i % (H_ - IN_)] = 0.f;
        __syncthreads();

        for (int l = 0; l < L_; ++l) {
            // ---- weight half into NAMED registers (no array -> no scratch) ----
            const float4* wp = (const float4*)(wbuf + (((size_t)l * 2 + (isA ? 0 : 1)) * G4 + g) * H_);
            float4 w00 = wp[0],  w01 = wp[1],  w02 = wp[2],  w03 = wp[3],  w04 = wp[4];
            float4 w05 = wp[5],  w06 = wp[6],  w07 = wp[7],  w08 = wp[8],  w09 = wp[9];
            float4 w10 = wp[10], w11 = wp[11], w12 = wp[12], w13 = wp[13], w14 = wp[14];
            float4 w15 = wp[15], w16 = wp[16], w17 = wp[17], w18 = wp[18], w19 = wp[19];
            const float bias = isA ? bbuf[l * G4 + g] : 0.f;
            float* __restrict__ gdst = isA ? gshA : gshB;

            if (tid < H_) hs[tid] = hstate[l][tid];
            float creg = (tid < H_) ? cstate[l][tid] : 0.f;
            __syncthreads();

            for (int t = 0; t < CH; ++t) {
                const float4* s4 = isA ? (const float4*)hist[t] : (const float4*)hs;
                float a0 = bias, a1 = 0.f, a2 = 0.f, a3 = 0.f;
#define FMA4(W, I) { float4 v = s4[I]; a0 += W.x * v.x; a1 += W.y * v.y; a2 += W.z * v.z; a3 += W.w * v.w; }
                FMA4(w00, 0)  FMA4(w01, 1)  FMA4(w02, 2)  FMA4(w03, 3)  FMA4(w04, 4)
                FMA4(w05, 5)  FMA4(w06, 6)  FMA4(w07, 7)  FMA4(w08, 8)  FMA4(w09, 9)
                FMA4(w10, 10) FMA4(w11, 11) FMA4(w12, 12) FMA4(w13, 13) FMA4(w14, 14)
                FMA4(w15, 15) FMA4(w16, 16) FMA4(w17, 17) FMA4(w18, 18) FMA4(w19, 19)
#undef FMA4
                gdst[g] = (a0 + a1) + (a2 + a3);
                __syncthreads();   // gsh ready; all reads of hist[t]/hs done

                if (tid < H_) {
                    float gi = sigm(gshA[tid] + gshB[tid]);
                    float gf = sigm(gshA[tid + H_] + gshB[tid + H_]);
                    float gg = tanhfast(gshA[tid + 2 * H_] + gshB[tid + 2 * H_]);
                    float go = sigm(gshA[tid + 3 * H_] + gshB[tid + 3 * H_]);
                    creg = gf * creg + gi * gg;
                    float h = go * tanhfast(creg);
                    hs[tid] = h;
                    hist[t][tid] = h;   // in-place: this t already consumed this layer
                }
                __syncthreads();   // hs / hist[t] ready
            }

            if (tid < H_) { hstate[l][tid] = hs[tid]; cstate[l][tid] = creg; }
            __syncthreads();
        }
    }

    // fc on the final hidden state (in hs)
    if (tid < NC_) {
        float acc = fcb[tid];
#pragma unroll
        for (int j = 0; j < H_; ++j) acc += fcw[tid * H_ + j] * hs[j];
        out[b * NC_ + tid] = acc;
    }
}

extern "C" void kernel_launch(void* const* d_in, const int* in_sizes, int n_in,
                              void* d_out, int out_size, void* d_ws, size_t ws_size,
                              hipStream_t stream) {
    const float* x    = (const float*)d_in[0];
    const float* Wih0 = (const float*)d_in[1];
    const float* WihR = (const float*)d_in[2];
    const float* Whh  = (const float*)d_in[3];
    const float* bih  = (const float*)d_in[4];
    const float* bhh  = (const float*)d_in[5];
    const float* fcw  = (const float*)d_in[6];
    const float* fcb  = (const float*)d_in[7];

    float* wbuf = (float*)d_ws;                     // 512000 floats
    float* bbuf = wbuf + L_ * 2 * G4 * H_;          // 3200 floats

    prep_kernel<<<dim3((L_ * 2 * G4 * H_ + 255) / 256), dim3(256), 0, stream>>>(
        Wih0, WihR, Whh, bih, bhh, wbuf, bbuf);

    lstm_stack_kernel<<<dim3(B_), dim3(TPB), 0, stream>>>(
        x, wbuf, bbuf, fcw, fcb, (float*)d_out);
}

// Round 4
// 5014.003 us; speedup vs baseline: 4.4188x; 1.0853x over previous
//
#include <hip/hip_runtime.h>

#define B_   256
#define T_   512
#define IN_  34
#define H_   80
#define L_   10
#define NC_  5
#define G4   320        // 4*H
#define TPB  640        // 2 threads per gate row: A half (W_ih) + B half (W_hh)
#define CH   256        // chunk timesteps held in LDS
#define NCH  2          // T_/CH

__device__ __forceinline__ float sigm(float x)     { return 1.f / (1.f + __expf(-x)); }
__device__ __forceinline__ float tanhfast(float x) { return 1.f - 2.f / (__expf(2.f * x) + 1.f); }

// Pack weights into branch-free layout: wbuf[l][half][g][k], half 0 = W_ih (layer0
// zero-padded 34->80), half 1 = W_hh. bbuf[l][g] = b_ih + b_hh.
__global__ void prep_kernel(const float* __restrict__ Wih0, const float* __restrict__ WihR,
                            const float* __restrict__ Whh,  const float* __restrict__ bih,
                            const float* __restrict__ bhh,
                            float* __restrict__ wbuf, float* __restrict__ bbuf) {
    int i = blockIdx.x * 256 + threadIdx.x;
    const int NW = L_ * 2 * G4 * H_;   // 512000
    if (i < NW) {
        int k = i % H_;
        int g = (i / H_) % G4;
        int half = (i / (H_ * G4)) % 2;
        int l = i / (H_ * G4 * 2);
        float v;
        if (half) v = Whh[((size_t)l * G4 + g) * H_ + k];
        else if (l == 0) v = (k < IN_) ? Wih0[g * IN_ + k] : 0.f;
        else v = WihR[((size_t)(l - 1) * G4 + g) * H_ + k];
        wbuf[i] = v;
    }
    if (i < L_ * G4) bbuf[i] = bih[i] + bhh[i];
}

// Force the loaded weight values to be VGPR-resident: the empty asm "defines"
// them, so the loads cannot be rematerialized/sunk into the time loop.
#define PIN4(W) asm volatile("" : "+v"(W.x), "+v"(W.y), "+v"(W.z), "+v"(W.w))

__global__ __launch_bounds__(TPB) void lstm_stack_kernel(
    const float* __restrict__ x,     // [B,T,34]
    const float* __restrict__ wbuf,  // [10][2][320][80]
    const float* __restrict__ bbuf,  // [10][320]
    const float* __restrict__ fcw,   // [5,80]
    const float* __restrict__ fcb,   // [5]
    float* __restrict__ out)         // [B,5]
{
    const int b   = blockIdx.x;
    const int tid = threadIdx.x;          // 0..639
    const bool isA = tid < G4;            // waves 0-4: W_ih half, waves 5-9: W_hh half
    const int g   = isA ? tid : tid - G4; // gate row 0..319

    __shared__ __align__(16) float hist[CH][H_];   // 80 KB inter-layer h history (in-place)
    __shared__ __align__(16) float hs[H_];         // h(t-1) of current layer
    __shared__ float gshA[G4];
    __shared__ float gshB[G4];
    __shared__ float hstate[L_][H_];
    __shared__ float cstate[L_][H_];

    for (int i = tid; i < L_ * H_; i += TPB) {
        (&hstate[0][0])[i] = 0.f;
        (&cstate[0][0])[i] = 0.f;
    }

    for (int c = 0; c < NCH; ++c) {
        __syncthreads();
        // stage x chunk into hist, zero-padded 34 -> 80 (layer 0 == generic layer)
        const float* xsrc = x + ((size_t)b * T_ + (size_t)c * CH) * IN_;
        for (int i = tid; i < CH * IN_; i += TPB) hist[i / IN_][i % IN_] = xsrc[i];
        for (int i = tid; i < CH * (H_ - IN_); i += TPB)
            hist[i / (H_ - IN_)][IN_ + i % (H_ - IN_)] = 0.f;
        __syncthreads();

        for (int l = 0; l < L_; ++l) {
            // ---- weight half into registers, PINNED so they stay resident ----
            const float4* wp = (const float4*)(wbuf + (((size_t)l * 2 + (isA ? 0 : 1)) * G4 + g) * H_);
            float4 w00 = wp[0],  w01 = wp[1],  w02 = wp[2],  w03 = wp[3],  w04 = wp[4];
            float4 w05 = wp[5],  w06 = wp[6],  w07 = wp[7],  w08 = wp[8],  w09 = wp[9];
            float4 w10 = wp[10], w11 = wp[11], w12 = wp[12], w13 = wp[13], w14 = wp[14];
            float4 w15 = wp[15], w16 = wp[16], w17 = wp[17], w18 = wp[18], w19 = wp[19];
            PIN4(w00); PIN4(w01); PIN4(w02); PIN4(w03); PIN4(w04);
            PIN4(w05); PIN4(w06); PIN4(w07); PIN4(w08); PIN4(w09);
            PIN4(w10); PIN4(w11); PIN4(w12); PIN4(w13); PIN4(w14);
            PIN4(w15); PIN4(w16); PIN4(w17); PIN4(w18); PIN4(w19);
            const float bias = isA ? bbuf[l * G4 + g] : 0.f;
            float* __restrict__ gdst = isA ? gshA : gshB;

            if (tid < H_) hs[tid] = hstate[l][tid];
            float creg = (tid < H_) ? cstate[l][tid] : 0.f;
            __syncthreads();

            for (int t = 0; t < CH; ++t) {
                const float4* s4 = isA ? (const float4*)hist[t] : (const float4*)hs;
                float a0 = bias, a1 = 0.f, a2 = 0.f, a3 = 0.f;
#define FMA4(W, I) { float4 v = s4[I]; a0 += W.x * v.x; a1 += W.y * v.y; a2 += W.z * v.z; a3 += W.w * v.w; }
                FMA4(w00, 0)  FMA4(w01, 1)  FMA4(w02, 2)  FMA4(w03, 3)  FMA4(w04, 4)
                FMA4(w05, 5)  FMA4(w06, 6)  FMA4(w07, 7)  FMA4(w08, 8)  FMA4(w09, 9)
                FMA4(w10, 10) FMA4(w11, 11) FMA4(w12, 12) FMA4(w13, 13) FMA4(w14, 14)
                FMA4(w15, 15) FMA4(w16, 16) FMA4(w17, 17) FMA4(w18, 18) FMA4(w19, 19)
#undef FMA4
                gdst[g] = (a0 + a1) + (a2 + a3);
                __syncthreads();   // gsh ready; all reads of hist[t]/hs done

                if (tid < H_) {
                    float gi = sigm(gshA[tid] + gshB[tid]);
                    float gf = sigm(gshA[tid + H_] + gshB[tid + H_]);
                    float gg = tanhfast(gshA[tid + 2 * H_] + gshB[tid + 2 * H_]);
                    float go = sigm(gshA[tid + 3 * H_] + gshB[tid + 3 * H_]);
                    creg = gf * creg + gi * gg;
                    float h = go * tanhfast(creg);
                    hs[tid] = h;
                    hist[t][tid] = h;   // in-place: this t already consumed this layer
                }
                __syncthreads();   // hs / hist[t] ready
            }

            if (tid < H_) { hstate[l][tid] = hs[tid]; cstate[l][tid] = creg; }
            __syncthreads();
        }
    }

    // fc on the final hidden state (in hs)
    if (tid < NC_) {
        float acc = fcb[tid];
#pragma unroll
        for (int j = 0; j < H_; ++j) acc += fcw[tid * H_ + j] * hs[j];
        out[b * NC_ + tid] = acc;
    }
}

extern "C" void kernel_launch(void* const* d_in, const int* in_sizes, int n_in,
                              void* d_out, int out_size, void* d_ws, size_t ws_size,
                              hipStream_t stream) {
    const float* x    = (const float*)d_in[0];
    const float* Wih0 = (const float*)d_in[1];
    const float* WihR = (const float*)d_in[2];
    const float* Whh  = (const float*)d_in[3];
    const float* bih  = (const float*)d_in[4];
    const float* bhh  = (const float*)d_in[5];
    const float* fcw  = (const float*)d_in[6];
    const float* fcb  = (const float*)d_in[7];

    float* wbuf = (float*)d_ws;                     // 512000 floats
    float* bbuf = wbuf + L_ * 2 * G4 * H_;          // 3200 floats

    prep_kernel<<<dim3((L_ * 2 * G4 * H_ + 255) / 256), dim3(256), 0, stream>>>(
        Wih0, WihR, Whh, bih, bhh, wbuf, bbuf);

    lstm_stack_kernel<<<dim3(B_), dim3(TPB), 0, stream>>>(
        x, wbuf, bbuf, fcw, fcb, (float*)d_out);
}

// Round 5
// 4475.714 us; speedup vs baseline: 4.9503x; 1.1203x over previous
//
#include <hip/hip_runtime.h>

#define B_   256
#define T_   512
#define IN_  34
#define H_   80
#define L_   10
#define NC_  5
#define G4   320        // 4*H
#define TPB  320        // 160 x-threads + 160 h-threads, each owns TWO gate rows
#define CH   256        // chunk timesteps held in LDS
#define NCH  2          // T_/CH

__device__ __forceinline__ float sigm(float x)     { return 1.f / (1.f + __expf(-x)); }
__device__ __forceinline__ float tanhfast(float x) { return 1.f - 2.f / (__expf(2.f * x) + 1.f); }

// wbuf[l][half][row][k], half 0 = W_ih (layer0 zero-padded 34->80), half 1 = W_hh.
// bbuf[l][row] = b_ih + b_hh.
__global__ void prep_kernel(const float* __restrict__ Wih0, const float* __restrict__ WihR,
                            const float* __restrict__ Whh,  const float* __restrict__ bih,
                            const float* __restrict__ bhh,
                            float* __restrict__ wbuf, float* __restrict__ bbuf) {
    int i = blockIdx.x * 256 + threadIdx.x;
    const int NW = L_ * 2 * G4 * H_;   // 512000
    if (i < NW) {
        int k = i % H_;
        int g = (i / H_) % G4;
        int half = (i / (H_ * G4)) % 2;
        int l = i / (H_ * G4 * 2);
        float v;
        if (half) v = Whh[((size_t)l * G4 + g) * H_ + k];
        else if (l == 0) v = (k < IN_) ? Wih0[g * IN_ + k] : 0.f;
        else v = WihR[((size_t)(l - 1) * G4 + g) * H_ + k];
        wbuf[i] = v;
    }
    if (i < L_ * G4) bbuf[i] = bih[i] + bhh[i];
}

#define PIN4(W) asm volatile("" : "+v"(W.x), "+v"(W.y), "+v"(W.z), "+v"(W.w))

__global__ __launch_bounds__(TPB, 1) void lstm_stack_kernel(
    const float* __restrict__ x,     // [B,T,34]
    const float* __restrict__ wbuf,  // [10][2][320][80]
    const float* __restrict__ bbuf,  // [10][320]
    const float* __restrict__ fcw,   // [5,80]
    const float* __restrict__ fcb,   // [5]
    float* __restrict__ out)         // [B,5]
{
    const int b   = blockIdx.x;
    const int tid = threadIdx.x;        // 0..319
    const bool isX = tid < 160;         // x-half group (reads hist[t]) vs h-half group (reads hs)
    const int i   = isX ? tid : tid - 160;   // row-pair index 0..159 -> rows 2i, 2i+1

    __shared__ __align__(16) float hist[CH][H_];   // 80 KB inter-layer h history (in-place)
    __shared__ __align__(16) float hs[H_];
    __shared__ __align__(8)  float gshA[G4];
    __shared__ __align__(8)  float gshB[G4];
    __shared__ float hstate[L_][H_];
    __shared__ float cstate[L_][H_];

    for (int j = tid; j < L_ * H_; j += TPB) {
        (&hstate[0][0])[j] = 0.f;
        (&cstate[0][0])[j] = 0.f;
    }

    for (int c = 0; c < NCH; ++c) {
        __syncthreads();
        // stage x chunk into hist, zero-padded 34 -> 80 (layer 0 == generic layer)
        const float* xsrc = x + ((size_t)b * T_ + (size_t)c * CH) * IN_;
        for (int j = tid; j < CH * IN_; j += TPB) hist[j / IN_][j % IN_] = xsrc[j];
        for (int j = tid; j < CH * (H_ - IN_); j += TPB)
            hist[j / (H_ - IN_)][IN_ + j % (H_ - IN_)] = 0.f;
        __syncthreads();

        for (int l = 0; l < L_; ++l) {
            // ---- TWO weight rows (160 floats) into named registers, pinned ----
            const float4* wp = (const float4*)(wbuf + (((size_t)l * 2 + (isX ? 0 : 1)) * G4 + 2 * i) * H_);
#define WDECL(N) float4 w##N = wp[N];
            WDECL(0)  WDECL(1)  WDECL(2)  WDECL(3)  WDECL(4)  WDECL(5)  WDECL(6)  WDECL(7)
            WDECL(8)  WDECL(9)  WDECL(10) WDECL(11) WDECL(12) WDECL(13) WDECL(14) WDECL(15)
            WDECL(16) WDECL(17) WDECL(18) WDECL(19) WDECL(20) WDECL(21) WDECL(22) WDECL(23)
            WDECL(24) WDECL(25) WDECL(26) WDECL(27) WDECL(28) WDECL(29) WDECL(30) WDECL(31)
            WDECL(32) WDECL(33) WDECL(34) WDECL(35) WDECL(36) WDECL(37) WDECL(38) WDECL(39)
#undef WDECL
            PIN4(w0);  PIN4(w1);  PIN4(w2);  PIN4(w3);  PIN4(w4);  PIN4(w5);  PIN4(w6);  PIN4(w7);
            PIN4(w8);  PIN4(w9);  PIN4(w10); PIN4(w11); PIN4(w12); PIN4(w13); PIN4(w14); PIN4(w15);
            PIN4(w16); PIN4(w17); PIN4(w18); PIN4(w19); PIN4(w20); PIN4(w21); PIN4(w22); PIN4(w23);
            PIN4(w24); PIN4(w25); PIN4(w26); PIN4(w27); PIN4(w28); PIN4(w29); PIN4(w30); PIN4(w31);
            PIN4(w32); PIN4(w33); PIN4(w34); PIN4(w35); PIN4(w36); PIN4(w37); PIN4(w38); PIN4(w39);

            const float bias0 = isX ? bbuf[l * G4 + 2 * i]     : 0.f;
            const float bias1 = isX ? bbuf[l * G4 + 2 * i + 1] : 0.f;
            float2* __restrict__ gdst = (float2*)(isX ? gshA : gshB);

            if (tid < H_) hs[tid] = hstate[l][tid];
            float creg = (tid < H_) ? cstate[l][tid] : 0.f;
            __syncthreads();

            for (int t = 0; t < CH; ++t) {
                const float4* s4 = isX ? (const float4*)hist[t] : (const float4*)hs;
                float a0 = bias0, a1 = 0.f, a2 = 0.f, a3 = 0.f;   // row 2i
                float c0 = bias1, c1 = 0.f, c2 = 0.f, c3 = 0.f;   // row 2i+1
#define STEP(J, WA, WB) { float4 v = s4[J]; \
    a0 += WA.x * v.x; a1 += WA.y * v.y; a2 += WA.z * v.z; a3 += WA.w * v.w; \
    c0 += WB.x * v.x; c1 += WB.y * v.y; c2 += WB.z * v.z; c3 += WB.w * v.w; }
                STEP(0,  w0,  w20) STEP(1,  w1,  w21) STEP(2,  w2,  w22) STEP(3,  w3,  w23)
                STEP(4,  w4,  w24) STEP(5,  w5,  w25) STEP(6,  w6,  w26) STEP(7,  w7,  w27)
                STEP(8,  w8,  w28) STEP(9,  w9,  w29) STEP(10, w10, w30) STEP(11, w11, w31)
                STEP(12, w12, w32) STEP(13, w13, w33) STEP(14, w14, w34) STEP(15, w15, w35)
                STEP(16, w16, w36) STEP(17, w17, w37) STEP(18, w18, w38) STEP(19, w19, w39)
#undef STEP
                gdst[i] = make_float2((a0 + a1) + (a2 + a3), (c0 + c1) + (c2 + c3));
                __syncthreads();   // gates ready; all reads of hist[t]/hs done

                if (tid < H_) {
                    float gi = sigm(gshA[tid] + gshB[tid]);
                    float gf = sigm(gshA[tid + H_] + gshB[tid + H_]);
                    float gg = tanhfast(gshA[tid + 2 * H_] + gshB[tid + 2 * H_]);
                    float go = sigm(gshA[tid + 3 * H_] + gshB[tid + 3 * H_]);
                    creg = gf * creg + gi * gg;
                    float h = go * tanhfast(creg);
                    hs[tid] = h;
                    hist[t][tid] = h;   // in-place: this t already consumed this layer
                }
                __syncthreads();   // hs / hist[t] ready
            }

            if (tid < H_) { hstate[l][tid] = hs[tid]; cstate[l][tid] = creg; }
            __syncthreads();
        }
    }

    // fc on the final hidden state (in hs)
    if (tid < NC_) {
        float acc = fcb[tid];
#pragma unroll
        for (int j = 0; j < H_; ++j) acc += fcw[tid * H_ + j] * hs[j];
        out[b * NC_ + tid] = acc;
    }
}

extern "C" void kernel_launch(void* const* d_in, const int* in_sizes, int n_in,
                              void* d_out, int out_size, void* d_ws, size_t ws_size,
                              hipStream_t stream) {
    const float* x    = (const float*)d_in[0];
    const float* Wih0 = (const float*)d_in[1];
    const float* WihR = (const float*)d_in[2];
    const float* Whh  = (const float*)d_in[3];
    const float* bih  = (const float*)d_in[4];
    const float* bhh  = (const float*)d_in[5];
    const float* fcw  = (const float*)d_in[6];
    const float* fcb  = (const float*)d_in[7];

    float* wbuf = (float*)d_ws;                     // 512000 floats
    float* bbuf = wbuf + L_ * 2 * G4 * H_;          // 3200 floats

    prep_kernel<<<dim3((L_ * 2 * G4 * H_ + 255) / 256), dim3(256), 0, stream>>>(
        Wih0, WihR, Whh, bih, bhh, wbuf, bbuf);

    lstm_stack_kernel<<<dim3(B_), dim3(TPB), 0, stream>>>(
        x, wbuf, bbuf, fcw, fcb, (float*)d_out);
}